// Round 11
// baseline (321.714 us; speedup 1.0000x reference)
//
#include <hip/hip_runtime.h>
#include <math.h>

#define NEG 0.2f

typedef short bf16x8 __attribute__((ext_vector_type(8)));
typedef float f32x4  __attribute__((ext_vector_type(4)));

// ---------------------------------------------------------------------------
// helpers
// ---------------------------------------------------------------------------
static __device__ __forceinline__ void fma4(float4& d, float s, const float4 w) {
    d.x = fmaf(s, w.x, d.x); d.y = fmaf(s, w.y, d.y);
    d.z = fmaf(s, w.z, d.z); d.w = fmaf(s, w.w, d.w);
}
static __device__ __forceinline__ unsigned short f2bf(float f) {   // RNE, finite
    unsigned int x = __float_as_uint(f);
    unsigned int r = (x + 0x7FFFu + ((x >> 16) & 1u)) >> 16;
    return (unsigned short)r;
}
static __device__ __forceinline__ float rlane(float v, int l) {
    return __int_as_float(__builtin_amdgcn_readlane(__float_as_int(v), l));
}
// Sum across each 16-lane DPP row; result broadcast to all 16 lanes.
#define DPP_ADD(x, ctrl) \
    ((x) + __int_as_float(__builtin_amdgcn_update_dpp( \
        __float_as_int(x), __float_as_int(x), (ctrl), 0xF, 0xF, true)))
static __device__ __forceinline__ float rowsum16(float v) {
    v = DPP_ADD(v, 0xB1);   // quad_perm xor1
    v = DPP_ADD(v, 0x4E);   // quad_perm xor2
    v = DPP_ADD(v, 0x141);  // row_half_mirror
    v = DPP_ADD(v, 0x140);  // row_mirror
    return v;
}

// ---------------------------------------------------------------------------
// CSR build (separate dispatches; cooperative grid.sync was ~120us/sync, R7)
// ---------------------------------------------------------------------------
__global__ void k_hist_wt(const int* __restrict__ dst_s, int Es,
                          const int* __restrict__ dst_n, int En,
                          int* __restrict__ deg_s, int* __restrict__ deg_n,
                          const float* __restrict__ W, unsigned short* __restrict__ Wt) {
    int i = blockIdx.x * 256 + threadIdx.x;
    if (i < Es) atomicAdd(&deg_s[dst_s[i]], 1);
    int j = i - Es;
    if (j >= 0 && j < En) atomicAdd(&deg_n[dst_n[j]], 1);
    if (i < 512 * 256) {                 // W[512][256] f32 -> Wt[256][512] bf16
        int k = i >> 8, n = i & 255;
        Wt[(size_t)n * 512 + k] = f2bf(W[i]);
    }
}

__global__ __launch_bounds__(1024) void k_scan2(int* a, int na, int* b, int nb) {
    int* p = (blockIdx.x == 0) ? a : b;
    int n  = (blockIdx.x == 0) ? na : nb;
    __shared__ int sums[1024];
    int t = threadIdx.x;
    int C = (n + 1023) >> 10;
    int base = t * C;
    int s = 0;
    for (int j = 0; j < C; ++j) { int i = base + j; if (i < n) s += p[i]; }
    sums[t] = s;
    __syncthreads();
    for (int off = 1; off < 1024; off <<= 1) {
        int v = (t >= off) ? sums[t - off] : 0;
        __syncthreads();
        sums[t] += v;
        __syncthreads();
    }
    int run = (t == 0) ? 0 : sums[t - 1];
    for (int j = 0; j < C; ++j) {
        int i = base + j;
        if (i < n) { int v = p[i]; p[i] = run; run += v; }
    }
}

__global__ void k_scatter(const int* __restrict__ src_s, const int* __restrict__ dst_s, int Es,
                          const int* __restrict__ src_n, const int* __restrict__ dst_n, int En,
                          int* __restrict__ cur_s, int* __restrict__ cur_n,
                          int* __restrict__ csr_s, int* __restrict__ csr_n) {
    int i = blockIdx.x * 256 + threadIdx.x;
    if (i < Es) {
        int pos = atomicAdd(&cur_s[dst_s[i]], 1);
        csr_s[pos] = src_s[i];
    }
    int j = i - Es;
    if (j >= 0 && j < En) {
        int pos = atomicAdd(&cur_n[dst_n[j]], 1);
        csr_n[pos] = src_n[j];
    }
}

// ---------------------------------------------------------------------------
// GATv2 via MFMA with PER-HEAD softmax (R10's bug: it softmaxed over all
// heads jointly). 4 nodes/wave, 16/block. Per 16-edge chunk:
//   fs[16x256] = Xe[16x8] @ Ws[8x256] as 16 x mfma_f32_16x16x32_bf16,
//   K zero-padded (B-frag rows for quad!=0 read LDS zero row -> pad terms
//   vanish). C-init = fd+bd+bs broadcast -> MFMA emits leakyrelu input.
// Head h = tiles 4h..4h+3 (64 feats). Per head: 4-tile attn-dot partials,
// rowsum16 -> score(edge q*4+r, h) quad-uniform; exp + pad-mask; route
// (shfl+2 selects) and keep in lanes qv==h => lane (c,qv) holds
// p(edge c, head qv). lq += pm per chunk -> rowsum16 = per-head denom in
// that head's quad. acc8 += pm*xs (f32) -> rowsum16(acc8*inv) = s_h.
// Output dims d0=lane*4 belong to head lane>>4==qv, so the f32 projection
//   out = s_h @ Ws + bs + fr  uses the lane's own quad values directly.
// bf16 touches only the score path; accumulation/projection stay f32.
// ---------------------------------------------------------------------------
__global__ __launch_bounds__(256) void k_gat(
    const float* __restrict__ xsrc_s, const int* __restrict__ pfx_s, const int* __restrict__ csr_s,
    const float* __restrict__ Ws_s, const float* __restrict__ bs_s,
    const float* __restrict__ Wd_s, const float* __restrict__ bd_s,
    const float* __restrict__ at_s,
    const float* __restrict__ Wr_s, const float* __restrict__ br_s,
    const float* __restrict__ xsrc_n, const int* __restrict__ pfx_n, const int* __restrict__ csr_n,
    const float* __restrict__ Ws_n, const float* __restrict__ bs_n,
    const float* __restrict__ Wd_n, const float* __restrict__ bd_n,
    const float* __restrict__ at_n,
    const float* __restrict__ Wr_n, const float* __restrict__ br_n,
    const float* __restrict__ x_ag,
    unsigned short* __restrict__ xcat, int n_dst, int gNs)
{
    __shared__ __align__(16) unsigned short sWsT[257 * 8];  // Ws^T bf16; row 256 = zeros
    __shared__ __align__(16) float sFD[16][256];  // per node: x@Wd + bd + bs
    __shared__ __align__(16) float sFR[16][256];  // per node: x@Wr + br

    const bool seen = (int)blockIdx.x < gNs;
    const float* x_src = seen ? xsrc_s : xsrc_n;
    const int*   pfx   = seen ? pfx_s  : pfx_n;
    const int*   csr   = seen ? csr_s  : csr_n;
    const float* Ws    = seen ? Ws_s   : Ws_n;
    const float* bs    = seen ? bs_s   : bs_n;
    const float* Wd    = seen ? Wd_s   : Wd_n;
    const float* bd    = seen ? bd_s   : bd_n;
    const float* at    = seen ? at_s   : at_n;
    const float* Wr    = seen ? Wr_s   : Wr_n;
    const float* br    = seen ? br_s   : br_n;
    const int col = seen ? 0 : 256;
    const int blk = seen ? (int)blockIdx.x : (int)blockIdx.x - gNs;

    const int t = threadIdx.x;
    const int wave = t >> 6, lane = t & 63;
    const int c = lane & 15, qv = lane >> 4;
    const int d0 = lane * 4;

    // ---- block-coop: Ws[8][256] f32 -> sWsT[n][k] bf16; zero row 256
    {
        unsigned int pk[4];
#pragma unroll
        for (int h = 0; h < 4; ++h) {
            unsigned int lo = f2bf(Ws[(2 * h)     * 256 + t]);
            unsigned int hi = f2bf(Ws[(2 * h + 1) * 256 + t]);
            pk[h] = lo | (hi << 16);
        }
        *(uint4*)&sWsT[t * 8] = make_uint4(pk[0], pk[1], pk[2], pk[3]);
        if (t == 0) *(uint4*)&sWsT[256 * 8] = make_uint4(0u, 0u, 0u, 0u);
    }

    // ---- one-pass fd/fr for this wave's 4 nodes -> LDS
    const int nodeBase = blk * 16 + wave * 4;
    {
        int gn = nodeBase + qv; gn = (gn < n_dst) ? gn : n_dst - 1;
        float xag = x_ag[(size_t)gn * 16 + c];
        float4 bdv = *(const float4*)&bd[d0];
        float4 brv = *(const float4*)&br[d0];
        float4 bsv4 = *(const float4*)&bs[d0];
        float4 off0 = make_float4(bdv.x + bsv4.x, bdv.y + bsv4.y,
                                  bdv.z + bsv4.z, bdv.w + bsv4.w);
        float4 fd4[4], fr4[4];
#pragma unroll
        for (int j = 0; j < 4; ++j) { fd4[j] = off0; fr4[j] = brv; }
#pragma unroll
        for (int k = 0; k < 16; ++k) {
            float4 wd = *(const float4*)&Wd[k * 256 + d0];
            float4 wr = *(const float4*)&Wr[k * 256 + d0];
#pragma unroll
            for (int j = 0; j < 4; ++j) {
                float xk = rlane(xag, j * 16 + k);
                fma4(fd4[j], xk, wd);
                fma4(fr4[j], xk, wr);
            }
        }
#pragma unroll
        for (int j = 0; j < 4; ++j) {
            *(float4*)&sFD[wave * 4 + j][d0] = fd4[j];
            *(float4*)&sFR[wave * 4 + j][d0] = fr4[j];
        }
    }
    __syncthreads();

    // B-frag LDS row for this lane: real cols for quad 0, zero row otherwise
    const int bzero = (qv == 0) ? 0 : 256 * 8;   // short offset of zero row

    float atC[16];
#pragma unroll
    for (int T = 0; T < 16; ++T) atC[T] = at[T * 16 + c];
    const float4 bsv = *(const float4*)&bs[d0];

    // ---- prefetch edge ranges for the 4 nodes
    int e_start[4], e_end[4];
#pragma unroll
    for (int j = 0; j < 4; ++j) {
        int nd = nodeBase + j; nd = (nd < n_dst) ? nd : n_dst - 1;
        e_end[j]   = pfx[nd];
        e_start[j] = nd ? pfx[nd - 1] : 0;
    }

    for (int rep = 0; rep < 4; ++rep) {
        const int node = nodeBase + rep;
        if (node >= n_dst) break;
        const int start = e_start[rep];
        const int deg   = e_end[rep] - start;

        float fdC[16];
#pragma unroll
        for (int T = 0; T < 16; ++T) fdC[T] = sFD[wave * 4 + rep][T * 16 + c];

        float acc8[8] = {0.f, 0.f, 0.f, 0.f, 0.f, 0.f, 0.f, 0.f};
        float lq = 0.f;

        for (int base = 0; base < deg; base += 16) {
            int er = base + c; er = (er < deg) ? er : deg - 1;
            int idx = csr[start + er];
            const float* xr = &x_src[(size_t)idx * 8];
            float4 xa = *(const float4*)xr;
            float4 xb = *(const float4*)(xr + 4);

            unsigned int a0 = (unsigned int)f2bf(xa.x) | ((unsigned int)f2bf(xa.y) << 16);
            unsigned int a1 = (unsigned int)f2bf(xa.z) | ((unsigned int)f2bf(xa.w) << 16);
            unsigned int a2 = (unsigned int)f2bf(xb.x) | ((unsigned int)f2bf(xb.y) << 16);
            unsigned int a3 = (unsigned int)f2bf(xb.z) | ((unsigned int)f2bf(xb.w) << 16);
            bf16x8 Af = __builtin_bit_cast(bf16x8, make_uint4(a0, a1, a2, a3));

            const int dm   = deg - base - qv * 4;    // pad-edge mask (per quad)
            const int srcl = (c >> 2) << 4;          // route: quad c>>2, reg c&3
            float pm = 0.f;

#pragma unroll
            for (int h = 0; h < 4; ++h) {            // head h = tiles 4h..4h+3
                float sc0 = 0.f, sc1 = 0.f, sc2 = 0.f, sc3 = 0.f;
#pragma unroll
                for (int Tw = 0; Tw < 4; ++Tw) {
                    const int T = h * 4 + Tw;
                    bf16x8 Bf = *(const bf16x8*)&sWsT[bzero + (qv == 0 ? (T * 16 + c) * 8 : 0)];
                    f32x4 Cv = {fdC[T], fdC[T], fdC[T], fdC[T]};
                    Cv = __builtin_amdgcn_mfma_f32_16x16x32_bf16(Af, Bf, Cv, 0, 0, 0);
                    float v0 = Cv[0], v1 = Cv[1], v2 = Cv[2], v3 = Cv[3];
                    v0 = fmaxf(v0, NEG * v0); sc0 = fmaf(v0, atC[T], sc0);
                    v1 = fmaxf(v1, NEG * v1); sc1 = fmaf(v1, atC[T], sc1);
                    v2 = fmaxf(v2, NEG * v2); sc2 = fmaf(v2, atC[T], sc2);
                    v3 = fmaxf(v3, NEG * v3); sc3 = fmaf(v3, atC[T], sc3);
                }
                sc0 = rowsum16(sc0);   // score(edge qv*4+0, h), quad-uniform
                sc1 = rowsum16(sc1);
                sc2 = rowsum16(sc2);
                sc3 = rowsum16(sc3);

                float p0 = __expf(dm > 0 ? sc0 : -1e30f);   // no max shift:
                float p1 = __expf(dm > 1 ? sc1 : -1e30f);   // |sc| bounded
                float p2 = __expf(dm > 2 ? sc2 : -1e30f);   // (R6-9 verified)
                float p3 = __expf(dm > 3 ? sc3 : -1e30f);

                float g0 = __shfl(p0, srcl), g1 = __shfl(p1, srcl);
                float g2 = __shfl(p2, srcl), g3 = __shfl(p3, srcl);
                float s01 = (c & 1) ? g1 : g0;
                float s23 = (c & 1) ? g3 : g2;
                float routed = (c & 2) ? s23 : s01;   // p(edge c, head h)
                pm = (qv == h) ? routed : pm;         // keep own head only
            }

            lq += pm;
            acc8[0] = fmaf(pm, xa.x, acc8[0]);
            acc8[1] = fmaf(pm, xa.y, acc8[1]);
            acc8[2] = fmaf(pm, xa.z, acc8[2]);
            acc8[3] = fmaf(pm, xa.w, acc8[3]);
            acc8[4] = fmaf(pm, xb.x, acc8[4]);
            acc8[5] = fmaf(pm, xb.y, acc8[5]);
            acc8[6] = fmaf(pm, xb.z, acc8[6]);
            acc8[7] = fmaf(pm, xb.w, acc8[7]);
        }

        // per-head denominator: lives in this head's quad
        float l = rowsum16(lq);
        float inv = (l > 0.f) ? 1.f / l : 0.f;
        float ok  = (l > 0.f) ? 1.f : 0.f;    // zero in-degree: no bs term
#pragma unroll
        for (int j = 0; j < 8; ++j) acc8[j] = rowsum16(acc8[j] * inv);

        // out = s_h @ Ws (f32) + ok*bs + fr, relu, bf16.
        // d0's head == qv, and acc8 is quad-uniform == s_{qv} -> use directly.
        float4 o = *(const float4*)&sFR[wave * 4 + rep][d0];
        fma4(o, ok, bsv);
#pragma unroll
        for (int k = 0; k < 8; ++k)
            fma4(o, acc8[k], *(const float4*)&Ws[k * 256 + d0]);

        ushort4 u;
        u.x = f2bf(fmaxf(o.x, 0.f));
        u.y = f2bf(fmaxf(o.y, 0.f));
        u.z = f2bf(fmaxf(o.z, 0.f));
        u.w = f2bf(fmaxf(o.w, 0.f));
        *(ushort4*)&xcat[(size_t)node * 512 + col + d0] = u;
    }
}

// ---------------------------------------------------------------------------
// out = relu(X[M,512]bf16 @ W[512,256]bf16 + b) via mfma_f32_16x16x32_bf16.
// ---------------------------------------------------------------------------
__global__ __launch_bounds__(256) void k_mlp(
    const unsigned short* __restrict__ X, const unsigned short* __restrict__ Wt,
    const float* __restrict__ b, float* __restrict__ out, int M)
{
    const int t = threadIdx.x;
    const int wave = t >> 6, lane = t & 63;
    const int m16 = lane & 15, q = lane >> 4;
    const int rbase = blockIdx.x * 16;
    const int nbase = wave * 64;

    int rowa = rbase + m16; if (rowa >= M) rowa = M - 1;
    const unsigned short* xp = X + (size_t)rowa * 512 + q * 8;
    const unsigned short* w0 = Wt + (size_t)(nbase + m16) * 512 + q * 8;
    const unsigned short* w1 = w0 + 16 * 512;
    const unsigned short* w2 = w0 + 32 * 512;
    const unsigned short* w3 = w0 + 48 * 512;

    f32x4 ac0 = {0.f, 0.f, 0.f, 0.f}, ac1 = ac0, ac2 = ac0, ac3 = ac0;

#pragma unroll
    for (int k0 = 0; k0 < 512; k0 += 32) {
        bf16x8 a  = *(const bf16x8*)(xp + k0);
        bf16x8 b0 = *(const bf16x8*)(w0 + k0);
        bf16x8 b1 = *(const bf16x8*)(w1 + k0);
        bf16x8 b2 = *(const bf16x8*)(w2 + k0);
        bf16x8 b3 = *(const bf16x8*)(w3 + k0);
        ac0 = __builtin_amdgcn_mfma_f32_16x16x32_bf16(a, b0, ac0, 0, 0, 0);
        ac1 = __builtin_amdgcn_mfma_f32_16x16x32_bf16(a, b1, ac1, 0, 0, 0);
        ac2 = __builtin_amdgcn_mfma_f32_16x16x32_bf16(a, b2, ac2, 0, 0, 0);
        ac3 = __builtin_amdgcn_mfma_f32_16x16x32_bf16(a, b3, ac3, 0, 0, 0);
    }

#define EPI(AC, J) { \
        int coln = nbase + (J) * 16 + m16; \
        float bias = b[coln]; \
        _Pragma("unroll") \
        for (int r = 0; r < 4; ++r) { \
            int orow = rbase + q * 4 + r; \
            if (orow < M) \
                out[(size_t)orow * 256 + coln] = fmaxf(AC[r] + bias, 0.f); \
        } }
    EPI(ac0, 0) EPI(ac1, 1) EPI(ac2, 2) EPI(ac3, 3)
#undef EPI
}

// ---------------------------------------------------------------------------
extern "C" void kernel_launch(void* const* d_in, const int* in_sizes, int n_in,
                              void* d_out, int out_size, void* d_ws, size_t ws_size,
                              hipStream_t stream) {
    const float* x_gt   = (const float*)d_in[0];
    const float* x_ubs  = (const float*)d_in[1];
    const float* x_ag   = (const float*)d_in[2];
    const int* seen_src = (const int*)d_in[3];
    const int* seen_dst = (const int*)d_in[4];
    const int* near_src = (const int*)d_in[5];
    const int* near_dst = (const int*)d_in[6];
    const float* Ws_s = (const float*)d_in[7];  const float* bs_s = (const float*)d_in[8];
    const float* Wd_s = (const float*)d_in[9];  const float* bd_s = (const float*)d_in[10];
    const float* at_s = (const float*)d_in[11];
    const float* Wr_s = (const float*)d_in[12]; const float* br_s = (const float*)d_in[13];
    const float* Ws_n = (const float*)d_in[14]; const float* bs_n = (const float*)d_in[15];
    const float* Wd_n = (const float*)d_in[16]; const float* bd_n = (const float*)d_in[17];
    const float* at_n = (const float*)d_in[18];
    const float* Wr_n = (const float*)d_in[19]; const float* br_n = (const float*)d_in[20];
    const float* W_a  = (const float*)d_in[21]; const float* b_a  = (const float*)d_in[22];

    const int n_ag = in_sizes[2] / 16;
    const int E_s  = in_sizes[3];
    const int E_n  = in_sizes[5];

    char* ws = (char*)d_ws;
    int* cur_s = (int*)ws;              ws += (size_t)n_ag * 4;
    int* cur_n = (int*)ws;              ws += (size_t)n_ag * 4;
    int* csr_s = (int*)ws;              ws += (size_t)E_s * 4;
    int* csr_n = (int*)ws;              ws += (size_t)E_n * 4;
    unsigned short* xcat = (unsigned short*)ws;  ws += (size_t)n_ag * 512 * 2;
    unsigned short* Wt   = (unsigned short*)ws;  // [256][512] bf16

    hipMemsetAsync(cur_s, 0, (size_t)n_ag * 8, stream);  // cur_s, cur_n contiguous

    int gE = (E_s + E_n + 255) / 256;
    k_hist_wt<<<gE, 256, 0, stream>>>(seen_dst, E_s, near_dst, E_n, cur_s, cur_n, W_a, Wt);
    k_scan2<<<2, 1024, 0, stream>>>(cur_s, n_ag, cur_n, n_ag);
    k_scatter<<<gE, 256, 0, stream>>>(seen_src, seen_dst, E_s, near_src, near_dst, E_n,
                                      cur_s, cur_n, csr_s, csr_n);

    int gN = (n_ag + 15) / 16;   // 16 nodes per block (4 waves x 4 nodes)
    k_gat<<<2 * gN, 256, 0, stream>>>(
        x_gt,  cur_s, csr_s, Ws_s, bs_s, Wd_s, bd_s, at_s, Wr_s, br_s,
        x_ubs, cur_n, csr_n, Ws_n, bs_n, Wd_n, bd_n, at_n, Wr_n, br_n,
        x_ag, xcat, n_ag, gN);

    k_mlp<<<(n_ag + 15) / 16, 256, 0, stream>>>(xcat, Wt, b_a, (float*)d_out, n_ag);
}